// Round 16
// baseline (160.035 us; speedup 1.0000x reference)
//
#include <hip/hip_runtime.h>

// Transposed flash attention, f16 MFMA (16x16x32), no-max softmax, NO SPLIT-K.
// R26: T5 setprio around MFMA clusters on the current best (R24/R25: 78.9us
// main). Calibrated pipe math: MFMA pipe-occupancy 89k cyc/SIMD (42% @ 190k
// measured), VALU 70k (37%), LDS 65k -> ideal anti-phased wall ~89k = 37us.
// The 2x residual = PHASE ALIGNMENT: the 2 waves/SIMD (one per block) run
// identical code launched together -> MFMA bursts collide, VALU bursts
// collide, shared dead gaps. setprio(1) around ONLY the MFMA clusters
// (QKH/PVH) makes the in-burst wave win issue arbitration -> bursts
// serialize -> waves anti-phase, each one's exp gap filled by the other's
// MFMAs. m191 regime (independent-wave attn, +4-7%), NOT m190's lockstep
// null (our blocks aren't barrier-coupled). setprio was only ever tested
// here on the broken R13/R14 variants; never on the dual-state schedule.
// Numerics BIT-IDENTICAL (pure priority hint). Rest identical to R25.
// launch_bounds(256,2) -- NEVER more (R9: 7x spill).
// Failure read: flat/regression -> remove; all levers (occupancy, barriers,
// prefetch, interleave, VALU work, priority) then measured-out -> boundary.

#define NBATCH 16
#define SEQ    4096
#define DIM    64
#define BQ     128
#define BK     64
#define NKT    (SEQ / BK)      // 64 tiles, full K per block
#define NTILES (NBATCH * NKT)         // 1024
#define TILEH  4096                   // halfs per 64x64 tile image (8 KB)

#define QSCALE 0.180336879f   // 0.125 * log2(e)

typedef _Float16 half2_t __attribute__((ext_vector_type(2)));
typedef _Float16 half4_t __attribute__((ext_vector_type(4)));
typedef _Float16 half8_t __attribute__((ext_vector_type(8)));
typedef float    floatx4 __attribute__((ext_vector_type(4)));

__device__ inline float fast_exp2(float x) {
#if __has_builtin(__builtin_amdgcn_exp2f)
  return __builtin_amdgcn_exp2f(x);
#else
  return exp2f(x);
#endif
}
__device__ inline float fast_rcp(float x) {
#if __has_builtin(__builtin_amdgcn_rcpf)
  return __builtin_amdgcn_rcpf(x);
#else
  return 1.0f / x;
#endif
}

// swizzled offset in halfs for element (row, col) of a 64x64 half tile
__device__ inline int swz(int row, int col) {
  return row * 64 + ((((col >> 3) ^ ((row >> 1) & 7)) << 3) | (col & 7));
}

// async 16B global->LDS copy: lds dest is wave-uniform; HW adds lane*16
__device__ inline void async16(const void* g, void* l) {
  __builtin_amdgcn_global_load_lds(
      (const __attribute__((address_space(1))) void*)g,
      (__attribute__((address_space(3))) void*)l, 16, 0, 0);
}

// ---------------- prepack: K,V f32 -> per-tile f16 images ----------------
// (R20: K direct-to-global, V through LDS; image bytes identical to R19)
__global__ __launch_bounds__(256, 2)
void prepack_kv(const float* __restrict__ Kg, const float* __restrict__ Vg,
                _Float16* __restrict__ Kh, _Float16* __restrict__ Vh)
{
  __shared__ __align__(16) _Float16 sVi[TILEH];
  const int tid = threadIdx.x;
  const int t16 = tid & 15;
  const int kg  = tid >> 4;
  const int bt  = blockIdx.x;                 // b*64 + kt
  const float* Kt_ = Kg + (size_t)bt * BK * DIM;
  const float* Vt_ = Vg + (size_t)bt * BK * DIM;

  floatx4 kbuf[4], vbuf[4];
  #pragma unroll
  for (int i = 0; i < 4; ++i) {
    const int key = kg + 16 * i;
    kbuf[i] = *(const floatx4*)(Kt_ + key * DIM + t16 * 4);
    vbuf[i] = *(const floatx4*)(Vt_ + key * DIM + t16 * 4);
  }
  {                                           // V: [dim][slot] swizzled -> LDS
    const int vbase = (kg >> 2) * 8 + (kg & 3) * 2;
    #pragma unroll
    for (int e = 0; e < 4; ++e) {
      const int dim = t16 * 4 + e;
      half2_t h0; h0[0] = (_Float16)vbuf[0][e]; h0[1] = (_Float16)vbuf[1][e];
      half2_t h1; h1[0] = (_Float16)vbuf[2][e]; h1[1] = (_Float16)vbuf[3][e];
      *(half2_t*)&sVi[swz(dim, vbase)]      = h0;
      *(half2_t*)&sVi[swz(dim, vbase + 32)] = h1;
    }
  }
  {                                           // K: [key][dim] swizzled -> global
    _Float16* Ko = Kh + (size_t)bt * TILEH;
    #pragma unroll
    for (int i = 0; i < 4; ++i) {
      const int key = kg + 16 * i;
      half4_t h;
      #pragma unroll
      for (int j = 0; j < 4; ++j) h[j] = (_Float16)kbuf[i][j];
      *(half4_t*)&Ko[swz(key, t16 * 4)] = h;  // 16 lanes = one 128B row
    }
  }
  __syncthreads();
  half8_t* Vo = (half8_t*)(Vh + (size_t)bt * TILEH);
  const half8_t* Vs = (const half8_t*)sVi;
  Vo[tid] = Vs[tid]; Vo[tid + 256] = Vs[tid + 256];
}

// ---------------- main kernel: full-K per block, in-register normalize -----
__global__ __launch_bounds__(256, 2)
void attn_f16_flash(const float* __restrict__ Qg, const _Float16* __restrict__ Kh,
                    const _Float16* __restrict__ Vh, float* __restrict__ Og)
{
  __shared__ __align__(16) _Float16 sT[4][2 * TILEH];  // ring: [buf][ K | V ]

  const int tid  = threadIdx.x;
  const int wave = tid >> 6;
  const int lane = tid & 63;
  const int l16  = lane & 15;
  const int quad = lane >> 4;
  const int hK   = (l16 >> 1) & 7;

  // XCD-clustered decode (bijective over 512 blocks): XCD x = bid&7 gets
  // batches {x, x+8} only -> 2MB K/V image working set per 4MB XCD L2.
  const int bid  = blockIdx.x;
  const int x    = bid & 7;
  const int r    = bid >> 3;                // 0..63
  const int b    = x + ((r & 1) << 3);
  const int qt   = r >> 1;                  // 0..31
  const int q0   = qt * BQ + wave * 32;     // 32 rows per wave

  const float* Qb = Qg + ((size_t)b * SEQ + q0) * DIM;
  float*       Ob = Og + ((size_t)b * SEQ + q0) * DIM;

  // ---- Q fragments (B-operand of S^T = K*Q^T), pre-scaled ----
  half8_t qf[2][2];
  #pragma unroll
  for (int s = 0; s < 2; ++s)
    #pragma unroll
    for (int c = 0; c < 2; ++c) {
      const floatx4 f0 = *(const floatx4*)(Qb + (s * 16 + l16) * DIM + c * 32 + quad * 8);
      const floatx4 f1 = *(const floatx4*)(Qb + (s * 16 + l16) * DIM + c * 32 + quad * 8 + 4);
      half8_t h;
      #pragma unroll
      for (int j = 0; j < 4; ++j) h[j] = (_Float16)(f0[j] * QSCALE);
      #pragma unroll
      for (int j = 0; j < 4; ++j) h[4 + j] = (_Float16)(f1[j] * QSCALE);
      qf[s][c] = h;
    }

  // all-ones A-operand for the lsum MFMA (layout-independent: A=1 everywhere)
  half8_t vones;
  #pragma unroll
  for (int j = 0; j < 8; ++j) vones[j] = (_Float16)1.0f;
  // persistent zero C-operand: seeds each QKH accumulation (replaces the
  // per-h-block 16-reg zero-init; mfma(a,b,0) == init-0 + accumulate).
  const floatx4 fzero4 = (floatx4){0.f, 0.f, 0.f, 0.f};

  floatx4 oacc2[4][2];   // [dim-tile n][q-slab s]
  floatx4 lacc[2];       // row-sum accumulator (ones . P), per slab
  #pragma unroll
  for (int n = 0; n < 4; ++n)
    #pragma unroll
    for (int s = 0; s < 2; ++s) oacc2[n][s] = (floatx4){0.f, 0.f, 0.f, 0.f};
  #pragma unroll
  for (int s = 0; s < 2; ++s) lacc[s] = (floatx4){0.f, 0.f, 0.f, 0.f};

  // ---- async staging: 4 x 16B-per-lane copies per wave per tile ----
  #define ASYNC(KT, BUF)                                                       \
    do {                                                                       \
      const char* gk = (const char*)(Kh + ((size_t)b * NKT + (KT)) * TILEH)    \
                       + wave * 2048;                                          \
      const char* gv = (const char*)(Vh + ((size_t)b * NKT + (KT)) * TILEH)    \
                       + wave * 2048;                                          \
      char* lk = (char*)(&sT[BUF][0])     + wave * 2048;                       \
      char* lv = (char*)(&sT[BUF][TILEH]) + wave * 2048;                       \
      async16(gk + lane * 16,        lk);                                      \
      async16(gk + 1024 + lane * 16, lk + 1024);                               \
      async16(gv + lane * 16,        lv);                                      \
      async16(gv + 1024 + lane * 16, lv + 1024);                               \
    } while (0)

  // ---- QK^T of h-block H from ring buffer BUF into scX ----
  // c=0 pass seeds with fzero4; c=1 accumulates. T5: setprio(1) brackets
  // the MFMA cluster -> in-burst wave wins issue arbitration -> the two
  // co-resident blocks' waves anti-phase (burst collision removed).
  #define QKH(scX, BUF, H)                                                     \
    do {                                                                       \
      const _Float16* SKB = &sT[BUF][0];                                       \
      __builtin_amdgcn_s_setprio(1);                                           \
      _Pragma("unroll")                                                        \
      for (int k2 = 0; k2 < 2; ++k2) {                                         \
        const int nk = (H) * 2 + k2;                                           \
        const half8_t kf0 = *(const half8_t*)&SKB[(nk * 16 + l16) * 64 +       \
                                                  ((quad ^ hK) << 3)];         \
        const half8_t kf1 = *(const half8_t*)&SKB[(nk * 16 + l16) * 64 +       \
                                                  (((4 + quad) ^ hK) << 3)];   \
        _Pragma("unroll")                                                      \
        for (int s = 0; s < 2; ++s)                                            \
          scX[k2][s] = __builtin_amdgcn_mfma_f32_16x16x32_f16(                 \
              kf0, qf[s][0], fzero4, 0, 0, 0);                                 \
        _Pragma("unroll")                                                      \
        for (int s = 0; s < 2; ++s)                                            \
          scX[k2][s] = __builtin_amdgcn_mfma_f32_16x16x32_f16(                 \
              kf1, qf[s][1], scX[k2][s], 0, 0, 0);                             \
      }                                                                        \
      __builtin_amdgcn_s_setprio(0);                                           \
    } while (0)

  // ---- softmax exp of scX -> bfrX: 16 INDEPENDENT exp+cvt chains ----
  #define EXPH(scX, bfrX)                                                      \
    do {                                                                       \
      _Pragma("unroll")                                                        \
      for (int s = 0; s < 2; ++s) {                                            \
        half8_t bf;                                                            \
        _Pragma("unroll")                                                      \
        for (int j = 0; j < 8; ++j)                                            \
          bf[j] = (_Float16)fast_exp2(scX[j & 1][s][j >> 1]);                  \
        bfrX[s] = bf;                                                          \
      }                                                                        \
    } while (0)

  // ---- PV accumulate of h-block H from ring buffer BUF with bfrX ----
  // + ones-column MFMA: lacc[s][*] += column sums of P (row sums per q).
  #define PVH(bfrX, BUF, H)                                                    \
    do {                                                                       \
      const _Float16* SVB = &sT[BUF][TILEH];                                   \
      __builtin_amdgcn_s_setprio(1);                                           \
      _Pragma("unroll")                                                        \
      for (int n = 0; n < 4; ++n) {                                            \
        half8_t vf = *(const half8_t*)&SVB[(n * 16 + l16) * 64 +               \
                                           ((((H) * 4 + quad) ^ hK) << 3)];    \
        _Pragma("unroll")                                                      \
        for (int s = 0; s < 2; ++s)                                            \
          oacc2[n][s] = __builtin_amdgcn_mfma_f32_16x16x32_f16(                \
              vf, bfrX[s], oacc2[n][s], 0, 0, 0);                              \
      }                                                                        \
      _Pragma("unroll")                                                        \
      for (int s = 0; s < 2; ++s)                                              \
        lacc[s] = __builtin_amdgcn_mfma_f32_16x16x32_f16(                      \
            vones, bfrX[s], lacc[s], 0, 0, 0);                                 \
      __builtin_amdgcn_s_setprio(0);                                           \
    } while (0)

  // counted-vmcnt phase gate: my loads older than newest N done + barrier
  // => all waves' data for the gated tile landed. Loads stay in flight.
  #define GATE(N)                                                              \
    do {                                                                       \
      asm volatile("s_waitcnt vmcnt(" #N ")" ::: "memory");                    \
      __builtin_amdgcn_s_barrier();                                            \
      __builtin_amdgcn_sched_barrier(0);                                       \
    } while (0)

  floatx4 scA[2][2], scB[2][2];
  half8_t bfrA[2], bfrB[2];

  // one steady iteration with STATIC ring index CB (= TT & 3) and ASYNC.
  // At GATE: outstanding = tiles TT+1, TT+2 (8 loads) -> vmcnt(4) ensures
  // tile TT+1 landed; TT+2 stays in flight across the barrier.
  #define STEP(TT, CB)                                                         \
    do {                                                                       \
      QKH(scB, CB, 1);               /* matrix: tile TT, h1 */                 \
      EXPH(scA, bfrA);               /* VALU: overlaps QKH above */            \
      PVH(bfrA, CB, 0);              /* matrix: tile TT, h0 (+lsum) */         \
      GATE(4);                                                                 \
      ASYNC((TT) + 3, ((CB) + 3) & 3);                                         \
      QKH(scA, ((CB) + 1) & 3, 0);   /* tile TT+1, h0 (fresh buffer) */        \
      EXPH(scB, bfrB);                                                         \
      PVH(bfrB, CB, 1);              /* tile TT, h1 (WAR safe: stage */        \
    } while (0)                      /* target (CB+3)&3 != CB) */

  // ---------- prologue ----------
  ASYNC(0, 0);
  ASYNC(1, 1);
  GATE(4);                         // tile 0 landed; tile 1 in flight
  ASYNC(2, 2);
  QKH(scA, 0, 0);

  // ---------- pipelined main loop, unrolled x4 (tiles 0..59) ----------
  #pragma unroll 1
  for (int t = 0; t < NKT - 4; t += 4) {   // t = 0,4,...,56
    STEP(t + 0, 0);
    STEP(t + 1, 1);
    STEP(t + 2, 2);
    STEP(t + 3, 3);
  }
  STEP(60, 0);                     // tile 60; ASYNC(63) -> buf 3

  // ---------- t = 61 (no ASYNC: tile 64 doesn't exist) ----------
  QKH(scB, 1, 1);
  EXPH(scA, bfrA);
  PVH(bfrA, 1, 0);
  GATE(4);                         // outstanding = tiles 62,63 -> 62 landed
  QKH(scA, 2, 0);
  EXPH(scB, bfrB);
  PVH(bfrB, 1, 1);

  // ---------- epilogue: t = 62 then 63 ----------
  {
    QKH(scB, 2, 1);
    EXPH(scA, bfrA);
    PVH(bfrA, 2, 0);
    GATE(0);                       // only tile 63 outstanding: drain it
    QKH(scA, 3, 0);
    EXPH(scB, bfrB);
    PVH(bfrB, 2, 1);
  }
  {
    QKH(scB, 3, 1);
    EXPH(scA, bfrA);
    PVH(bfrA, 3, 0);
    EXPH(scB, bfrB);
    PVH(bfrB, 3, 1);
  }

  // ---------- epilogue: normalize + single O write (no shuffles) ----------
  // lacc[s][j] all equal per lane = full row sum for q-row s*16+l16.
  #pragma unroll
  for (int s = 0; s < 2; ++s) {
    const float inv = fast_rcp(lacc[s][0]);
    #pragma unroll
    for (int n = 0; n < 4; ++n) {
      floatx4 o = oacc2[n][s];
      #pragma unroll
      for (int j = 0; j < 4; ++j) o[j] *= inv;
      *(floatx4*)&Ob[(s * 16 + l16) * DIM + n * 16 + quad * 4] = o;
    }
  }

  #undef ASYNC
  #undef QKH
  #undef EXPH
  #undef PVH
  #undef GATE
  #undef STEP
}

extern "C" void kernel_launch(void* const* d_in, const int* in_sizes, int n_in,
                              void* d_out, int out_size, void* d_ws, size_t ws_size,
                              hipStream_t stream) {
  const float* Q = (const float*)d_in[0];
  const float* K = (const float*)d_in[1];
  const float* V = (const float*)d_in[2];
  float* O  = (float*)d_out;
  (void)in_sizes; (void)n_in; (void)out_size; (void)ws_size;

  // ws layout: Kh,Vh images (f16) only. total ~16.8 MB (R9 proved >=51 MB).
  _Float16* Kh = (_Float16*)d_ws;
  _Float16* Vh = Kh + (size_t)NTILES * TILEH;

  prepack_kv<<<dim3(NTILES), dim3(256), 0, stream>>>(K, V, Kh, Vh);
  attn_f16_flash<<<dim3(NBATCH * (SEQ / BQ)), dim3(256), 0, stream>>>(
      Q, Kh, Vh, O);
}

// Round 17
// 156.072 us; speedup vs baseline: 1.0254x; 1.0254x over previous
//
#include <hip/hip_runtime.h>

// Transposed flash attention, f16 MFMA (16x16x32), no-max softmax, NO SPLIT-K.
// R27 = EXACT REVERT to R24 (session best: 156.8us total / 78.9us main).
// R26's setprio REGRESSED (main 79->84.9, MfmaUtil 42.3->37.5): in 4-wave
// gated blocks, boosting a wave through its MFMA burst starves the other
// wave's ds_reads feeding its next burst -- m191's +4-7% only transfers to
// 1-wave-block attn, not this structure. Final lever ledger (17 rounds):
// occupancy null (R11/R12); barrier-free/direct-L2 -70% (R13/R14); counted
// vmcnt +1.5% (R15); exp||MFMA interleave null (R16/R17); combine-fusion
// poisoned by agent-fence L2 flush (R18); split-K delete WIN (R19); reg
// prefetch sunk by compiler (R21); lsum-via-ones-MFMA WIN -3.5us (R22);
// pkrtz neutral (R23); x4-unroll/static-ring WIN -2.8us (R24); zero-C
// neutral (R25); setprio -6us (R26). 78.9us main = ~885 TF effective, both
// pipes 42/38%, residual dead time = intrinsic dep-chain latency at 2
// waves/SIMD. Beyond here is the co-designed 8-wave/32x32 rework (HK
// structure), not reachable by increments. launch_bounds(256,2) -- NEVER
// more (R9: 7x spill).

#define NBATCH 16
#define SEQ    4096
#define DIM    64
#define BQ     128
#define BK     64
#define NKT    (SEQ / BK)      // 64 tiles, full K per block
#define NTILES (NBATCH * NKT)         // 1024
#define TILEH  4096                   // halfs per 64x64 tile image (8 KB)

#define QSCALE 0.180336879f   // 0.125 * log2(e)

typedef _Float16 half2_t __attribute__((ext_vector_type(2)));
typedef _Float16 half4_t __attribute__((ext_vector_type(4)));
typedef _Float16 half8_t __attribute__((ext_vector_type(8)));
typedef float    floatx4 __attribute__((ext_vector_type(4)));

__device__ inline float fast_exp2(float x) {
#if __has_builtin(__builtin_amdgcn_exp2f)
  return __builtin_amdgcn_exp2f(x);
#else
  return exp2f(x);
#endif
}
__device__ inline float fast_rcp(float x) {
#if __has_builtin(__builtin_amdgcn_rcpf)
  return __builtin_amdgcn_rcpf(x);
#else
  return 1.0f / x;
#endif
}

// swizzled offset in halfs for element (row, col) of a 64x64 half tile
__device__ inline int swz(int row, int col) {
  return row * 64 + ((((col >> 3) ^ ((row >> 1) & 7)) << 3) | (col & 7));
}

// async 16B global->LDS copy: lds dest is wave-uniform; HW adds lane*16
__device__ inline void async16(const void* g, void* l) {
  __builtin_amdgcn_global_load_lds(
      (const __attribute__((address_space(1))) void*)g,
      (__attribute__((address_space(3))) void*)l, 16, 0, 0);
}

// ---------------- prepack: K,V f32 -> per-tile f16 images ----------------
// (R20: K direct-to-global, V through LDS; image bytes identical to R19)
__global__ __launch_bounds__(256, 2)
void prepack_kv(const float* __restrict__ Kg, const float* __restrict__ Vg,
                _Float16* __restrict__ Kh, _Float16* __restrict__ Vh)
{
  __shared__ __align__(16) _Float16 sVi[TILEH];
  const int tid = threadIdx.x;
  const int t16 = tid & 15;
  const int kg  = tid >> 4;
  const int bt  = blockIdx.x;                 // b*64 + kt
  const float* Kt_ = Kg + (size_t)bt * BK * DIM;
  const float* Vt_ = Vg + (size_t)bt * BK * DIM;

  floatx4 kbuf[4], vbuf[4];
  #pragma unroll
  for (int i = 0; i < 4; ++i) {
    const int key = kg + 16 * i;
    kbuf[i] = *(const floatx4*)(Kt_ + key * DIM + t16 * 4);
    vbuf[i] = *(const floatx4*)(Vt_ + key * DIM + t16 * 4);
  }
  {                                           // V: [dim][slot] swizzled -> LDS
    const int vbase = (kg >> 2) * 8 + (kg & 3) * 2;
    #pragma unroll
    for (int e = 0; e < 4; ++e) {
      const int dim = t16 * 4 + e;
      half2_t h0; h0[0] = (_Float16)vbuf[0][e]; h0[1] = (_Float16)vbuf[1][e];
      half2_t h1; h1[0] = (_Float16)vbuf[2][e]; h1[1] = (_Float16)vbuf[3][e];
      *(half2_t*)&sVi[swz(dim, vbase)]      = h0;
      *(half2_t*)&sVi[swz(dim, vbase + 32)] = h1;
    }
  }
  {                                           // K: [key][dim] swizzled -> global
    _Float16* Ko = Kh + (size_t)bt * TILEH;
    #pragma unroll
    for (int i = 0; i < 4; ++i) {
      const int key = kg + 16 * i;
      half4_t h;
      #pragma unroll
      for (int j = 0; j < 4; ++j) h[j] = (_Float16)kbuf[i][j];
      *(half4_t*)&Ko[swz(key, t16 * 4)] = h;  // 16 lanes = one 128B row
    }
  }
  __syncthreads();
  half8_t* Vo = (half8_t*)(Vh + (size_t)bt * TILEH);
  const half8_t* Vs = (const half8_t*)sVi;
  Vo[tid] = Vs[tid]; Vo[tid + 256] = Vs[tid + 256];
}

// ---------------- main kernel: full-K per block, in-register normalize -----
__global__ __launch_bounds__(256, 2)
void attn_f16_flash(const float* __restrict__ Qg, const _Float16* __restrict__ Kh,
                    const _Float16* __restrict__ Vh, float* __restrict__ Og)
{
  __shared__ __align__(16) _Float16 sT[4][2 * TILEH];  // ring: [buf][ K | V ]

  const int tid  = threadIdx.x;
  const int wave = tid >> 6;
  const int lane = tid & 63;
  const int l16  = lane & 15;
  const int quad = lane >> 4;
  const int hK   = (l16 >> 1) & 7;

  // XCD-clustered decode (bijective over 512 blocks): XCD x = bid&7 gets
  // batches {x, x+8} only -> 2MB K/V image working set per 4MB XCD L2.
  const int bid  = blockIdx.x;
  const int x    = bid & 7;
  const int r    = bid >> 3;                // 0..63
  const int b    = x + ((r & 1) << 3);
  const int qt   = r >> 1;                  // 0..31
  const int q0   = qt * BQ + wave * 32;     // 32 rows per wave

  const float* Qb = Qg + ((size_t)b * SEQ + q0) * DIM;
  float*       Ob = Og + ((size_t)b * SEQ + q0) * DIM;

  // ---- Q fragments (B-operand of S^T = K*Q^T), pre-scaled ----
  half8_t qf[2][2];
  #pragma unroll
  for (int s = 0; s < 2; ++s)
    #pragma unroll
    for (int c = 0; c < 2; ++c) {
      const floatx4 f0 = *(const floatx4*)(Qb + (s * 16 + l16) * DIM + c * 32 + quad * 8);
      const floatx4 f1 = *(const floatx4*)(Qb + (s * 16 + l16) * DIM + c * 32 + quad * 8 + 4);
      half8_t h;
      #pragma unroll
      for (int j = 0; j < 4; ++j) h[j] = (_Float16)(f0[j] * QSCALE);
      #pragma unroll
      for (int j = 0; j < 4; ++j) h[4 + j] = (_Float16)(f1[j] * QSCALE);
      qf[s][c] = h;
    }

  // all-ones A-operand for the lsum MFMA (layout-independent: A=1 everywhere)
  half8_t vones;
  #pragma unroll
  for (int j = 0; j < 8; ++j) vones[j] = (_Float16)1.0f;

  floatx4 oacc2[4][2];   // [dim-tile n][q-slab s]
  floatx4 lacc[2];       // row-sum accumulator (ones . P), per slab
  #pragma unroll
  for (int n = 0; n < 4; ++n)
    #pragma unroll
    for (int s = 0; s < 2; ++s) oacc2[n][s] = (floatx4){0.f, 0.f, 0.f, 0.f};
  #pragma unroll
  for (int s = 0; s < 2; ++s) lacc[s] = (floatx4){0.f, 0.f, 0.f, 0.f};

  // ---- async staging: 4 x 16B-per-lane copies per wave per tile ----
  #define ASYNC(KT, BUF)                                                       \
    do {                                                                       \
      const char* gk = (const char*)(Kh + ((size_t)b * NKT + (KT)) * TILEH)    \
                       + wave * 2048;                                          \
      const char* gv = (const char*)(Vh + ((size_t)b * NKT + (KT)) * TILEH)    \
                       + wave * 2048;                                          \
      char* lk = (char*)(&sT[BUF][0])     + wave * 2048;                       \
      char* lv = (char*)(&sT[BUF][TILEH]) + wave * 2048;                       \
      async16(gk + lane * 16,        lk);                                      \
      async16(gk + 1024 + lane * 16, lk + 1024);                               \
      async16(gv + lane * 16,        lv);                                      \
      async16(gv + 1024 + lane * 16, lv + 1024);                               \
    } while (0)

  // ---- QK^T of h-block H from ring buffer BUF into scX ----
  #define QKH(scX, BUF, H)                                                     \
    do {                                                                       \
      const _Float16* SKB = &sT[BUF][0];                                       \
      _Pragma("unroll")                                                        \
      for (int k2 = 0; k2 < 2; ++k2)                                           \
        _Pragma("unroll")                                                      \
        for (int s = 0; s < 2; ++s) scX[k2][s] = (floatx4){0.f, 0.f, 0.f, 0.f};\
      _Pragma("unroll")                                                        \
      for (int k2 = 0; k2 < 2; ++k2) {                                         \
        const int nk = (H) * 2 + k2;                                           \
        _Pragma("unroll")                                                      \
        for (int c = 0; c < 2; ++c) {                                          \
          half8_t kf = *(const half8_t*)&SKB[(nk * 16 + l16) * 64 +            \
                                             (((c * 4 + quad) ^ hK) << 3)];    \
          _Pragma("unroll")                                                    \
          for (int s = 0; s < 2; ++s)                                          \
            scX[k2][s] = __builtin_amdgcn_mfma_f32_16x16x32_f16(               \
                kf, qf[s][c], scX[k2][s], 0, 0, 0);                            \
        }                                                                      \
      }                                                                        \
    } while (0)

  // ---- softmax exp of scX -> bfrX: 16 INDEPENDENT exp+cvt chains ----
  #define EXPH(scX, bfrX)                                                      \
    do {                                                                       \
      _Pragma("unroll")                                                        \
      for (int s = 0; s < 2; ++s) {                                            \
        half8_t bf;                                                            \
        _Pragma("unroll")                                                      \
        for (int j = 0; j < 8; ++j)                                            \
          bf[j] = (_Float16)fast_exp2(scX[j & 1][s][j >> 1]);                  \
        bfrX[s] = bf;                                                          \
      }                                                                        \
    } while (0)

  // ---- PV accumulate of h-block H from ring buffer BUF with bfrX ----
  // + ones-column MFMA: lacc[s][*] += column sums of P (row sums per q).
  #define PVH(bfrX, BUF, H)                                                    \
    do {                                                                       \
      const _Float16* SVB = &sT[BUF][TILEH];                                   \
      _Pragma("unroll")                                                        \
      for (int n = 0; n < 4; ++n) {                                            \
        half8_t vf = *(const half8_t*)&SVB[(n * 16 + l16) * 64 +               \
                                           ((((H) * 4 + quad) ^ hK) << 3)];    \
        _Pragma("unroll")                                                      \
        for (int s = 0; s < 2; ++s)                                            \
          oacc2[n][s] = __builtin_amdgcn_mfma_f32_16x16x32_f16(                \
              vf, bfrX[s], oacc2[n][s], 0, 0, 0);                              \
      }                                                                        \
      _Pragma("unroll")                                                        \
      for (int s = 0; s < 2; ++s)                                              \
        lacc[s] = __builtin_amdgcn_mfma_f32_16x16x32_f16(                      \
            vones, bfrX[s], lacc[s], 0, 0, 0);                                 \
    } while (0)

  // counted-vmcnt phase gate: my loads older than newest N done + barrier
  // => all waves' data for the gated tile landed. Loads stay in flight.
  #define GATE(N)                                                              \
    do {                                                                       \
      asm volatile("s_waitcnt vmcnt(" #N ")" ::: "memory");                    \
      __builtin_amdgcn_s_barrier();                                            \
      __builtin_amdgcn_sched_barrier(0);                                       \
    } while (0)

  floatx4 scA[2][2], scB[2][2];
  half8_t bfrA[2], bfrB[2];

  // one steady iteration with STATIC ring index CB (= TT & 3) and ASYNC.
  // At GATE: outstanding = tiles TT+1, TT+2 (8 loads) -> vmcnt(4) ensures
  // tile TT+1 landed; TT+2 stays in flight across the barrier.
  #define STEP(TT, CB)                                                         \
    do {                                                                       \
      QKH(scB, CB, 1);               /* matrix: tile TT, h1 */                 \
      EXPH(scA, bfrA);               /* VALU: overlaps QKH above */            \
      PVH(bfrA, CB, 0);              /* matrix: tile TT, h0 (+lsum) */         \
      GATE(4);                                                                 \
      ASYNC((TT) + 3, ((CB) + 3) & 3);                                         \
      QKH(scA, ((CB) + 1) & 3, 0);   /* tile TT+1, h0 (fresh buffer) */        \
      EXPH(scB, bfrB);                                                         \
      PVH(bfrB, CB, 1);              /* tile TT, h1 (WAR safe: stage */        \
    } while (0)                      /* target (CB+3)&3 != CB) */

  // ---------- prologue ----------
  ASYNC(0, 0);
  ASYNC(1, 1);
  GATE(4);                         // tile 0 landed; tile 1 in flight
  ASYNC(2, 2);
  QKH(scA, 0, 0);

  // ---------- pipelined main loop, unrolled x4 (tiles 0..59) ----------
  #pragma unroll 1
  for (int t = 0; t < NKT - 4; t += 4) {   // t = 0,4,...,56
    STEP(t + 0, 0);
    STEP(t + 1, 1);
    STEP(t + 2, 2);
    STEP(t + 3, 3);
  }
  STEP(60, 0);                     // tile 60; ASYNC(63) -> buf 3

  // ---------- t = 61 (no ASYNC: tile 64 doesn't exist) ----------
  QKH(scB, 1, 1);
  EXPH(scA, bfrA);
  PVH(bfrA, 1, 0);
  GATE(4);                         // outstanding = tiles 62,63 -> 62 landed
  QKH(scA, 2, 0);
  EXPH(scB, bfrB);
  PVH(bfrB, 1, 1);

  // ---------- epilogue: t = 62 then 63 ----------
  {
    QKH(scB, 2, 1);
    EXPH(scA, bfrA);
    PVH(bfrA, 2, 0);
    GATE(0);                       // only tile 63 outstanding: drain it
    QKH(scA, 3, 0);
    EXPH(scB, bfrB);
    PVH(bfrB, 2, 1);
  }
  {
    QKH(scB, 3, 1);
    EXPH(scA, bfrA);
    PVH(bfrA, 3, 0);
    EXPH(scB, bfrB);
    PVH(bfrB, 3, 1);
  }

  // ---------- epilogue: normalize + single O write (no shuffles) ----------
  // lacc[s][j] all equal per lane = full row sum for q-row s*16+l16.
  #pragma unroll
  for (int s = 0; s < 2; ++s) {
    const float inv = fast_rcp(lacc[s][0]);
    #pragma unroll
    for (int n = 0; n < 4; ++n) {
      floatx4 o = oacc2[n][s];
      #pragma unroll
      for (int j = 0; j < 4; ++j) o[j] *= inv;
      *(floatx4*)&Ob[(s * 16 + l16) * DIM + n * 16 + quad * 4] = o;
    }
  }

  #undef ASYNC
  #undef QKH
  #undef EXPH
  #undef PVH
  #undef GATE
  #undef STEP
}

extern "C" void kernel_launch(void* const* d_in, const int* in_sizes, int n_in,
                              void* d_out, int out_size, void* d_ws, size_t ws_size,
                              hipStream_t stream) {
  const float* Q = (const float*)d_in[0];
  const float* K = (const float*)d_in[1];
  const float* V = (const float*)d_in[2];
  float* O  = (float*)d_out;
  (void)in_sizes; (void)n_in; (void)out_size; (void)ws_size;

  // ws layout: Kh,Vh images (f16) only. total ~16.8 MB (R9 proved >=51 MB).
  _Float16* Kh = (_Float16*)d_ws;
  _Float16* Vh = Kh + (size_t)NTILES * TILEH;

  prepack_kv<<<dim3(NTILES), dim3(256), 0, stream>>>(K, V, Kh, Vh);
  attn_f16_flash<<<dim3(NBATCH * (SEQ / BQ)), dim3(256), 0, stream>>>(
      Q, Kh, Vh, O);
}